// Round 2
// baseline (113.686 us; speedup 1.0000x reference)
//
#include <hip/hip_runtime.h>

#define IMG_H 200
#define IMG_W 200
#define VOLD  256          // volume is 256^3, strides: x<<16, y<<8, z
#define KPH   8            // threads (phases) per pixel
#define PPB   (256 / KPH)  // 32 pixels per 256-thread block
#define NPIX  (IMG_H * IMG_W)
#define NBLK  (NPIX / PPB) // 1250 (exact)
#define NXCD  8

__global__ __launch_bounds__(256) void drr_kernel(
    const float* __restrict__ vol,
    const float* __restrict__ kinv,   // [3][3]
    const float* __restrict__ rt,     // [4][4]
    const float* __restrict__ sddp,   // [1]
    const float* __restrict__ aff,    // [4][4]
    const int*   __restrict__ nsp,    // [1]
    float*       __restrict__ out)    // [H*W]
{
    // bijective XCD-chunked swizzle (m204): contiguous detector rows per XCD
    int b = blockIdx.x;
    {
        const int q = NBLK / NXCD;          // 156
        const int r = NBLK % NXCD;          // 2
        const int xcd = b % NXCD;
        const int idx = b / NXCD;
        b = (xcd < r) ? xcd * (q + 1) + idx
                      : r * (q + 1) + (xcd - r) * q + idx;
    }

    const int p     = b * PPB + ((int)threadIdx.x >> 3);  // pixel index
    const int phase = (int)threadIdx.x & (KPH - 1);
    if (p >= NPIX) return;

    const int   N     = nsp[0];
    const float sdd   = sddp[0];
    const float invN1 = 1.0f / (float)(N - 1);

    const float u = (float)(p % IMG_W);
    const float v = (float)(p / IMG_W);

    // tgt_cam = K^-1 * (u,v,1) * sdd
    const float tcx = (kinv[0]*u + kinv[1]*v + kinv[2]) * sdd;
    const float tcy = (kinv[3]*u + kinv[4]*v + kinv[5]) * sdd;
    const float tcz = (kinv[6]*u + kinv[7]*v + kinv[8]) * sdd;

    // ray = R * tgt_cam ; src = t
    const float rx = rt[0]*tcx + rt[1]*tcy + rt[2]*tcz;
    const float ry = rt[4]*tcx + rt[5]*tcy + rt[6]*tcz;
    const float rz = rt[8]*tcx + rt[9]*tcy + rt[10]*tcz;
    const float sx = rt[3], sy = rt[7], sz = rt[11];

    // voxel-space: vox(t) = base + t * dir
    const float bx = aff[0]*sx + aff[1]*sy + aff[2]*sz  + aff[3];
    const float by = aff[4]*sx + aff[5]*sy + aff[6]*sz  + aff[7];
    const float bz = aff[8]*sx + aff[9]*sy + aff[10]*sz + aff[11];
    const float dx = aff[0]*rx + aff[1]*ry + aff[2]*rz;
    const float dy = aff[4]*rx + aff[5]*ry + aff[6]*rz;
    const float dz = aff[8]*rx + aff[9]*ry + aff[10]*rz;

    // per-SAMPLE steps (coords computed as fmaf(sf, d*s, b*) with integer sf)
    const float dxs = dx * invN1, dys = dy * invN1, dzs = dz * invN1;

    // ---- two clip windows from one rcp per axis:
    //  outer (-1, 256): sample may be nonzero (same as before)
    //  inner (0.01, 254.95): ALL 8 corners provably in-bounds -> fast path
    float t0 = 0.0f, t1 = 1.0f;
    float u0 = 0.0f, u1 = 1.0f;
    {
        const float bs[3] = {bx, by, bz};
        const float ds[3] = {dx, dy, dz};
        #pragma unroll
        for (int d = 0; d < 3; ++d) {
            const float bq = bs[d];
            const float dd = ds[d];
            if (fabsf(dd) > 1e-20f) {
                const float rdd = __frcp_rn(dd);
                const float ta = (-1.0f   - bq) * rdd;
                const float tb = (256.0f  - bq) * rdd;
                t0 = fmaxf(t0, fminf(ta, tb));
                t1 = fminf(t1, fmaxf(ta, tb));
                const float ua = (0.01f   - bq) * rdd;
                const float ub = (254.95f - bq) * rdd;
                u0 = fmaxf(u0, fminf(ua, ub));
                u1 = fminf(u1, fmaxf(ua, ub));
            } else {
                if (bq <= -1.0f  || bq >= 256.0f)   { t0 = 1.0f; t1 = -1.0f; }
                if (bq <= 0.01f  || bq >= 254.95f)  { u0 = 1.0f; u1 = -1.0f; }
            }
        }
    }
    int s_lo = 0, s_hi = -1;
    if (t0 <= t1) {
        s_lo = max((int)floorf(t0 * (float)(N - 1)) - 1, 0);
        s_hi = min((int)ceilf (t1 * (float)(N - 1)) + 1, N - 1);
    }
    int s_in, s_out;
    if (u0 <= u1) {
        s_in  = (int)ceilf (u0 * (float)(N - 1)) + 1;   // conservative shrink
        s_out = (int)floorf(u1 * (float)(N - 1)) - 1;
    } else {
        s_in = s_hi + 1; s_out = s_lo - 1;              // no fast region
    }
    const int sA_end = min(s_in,  s_hi + 1);  // checked prologue: s <  sA_end
    const int sB_end = min(s_out, s_hi);      // fast interior:    s <= sB_end
                                              // checked epilogue: s <= s_hi

    int   s   = s_lo + phase;
    float sf  = (float)s;
    float acc = 0.0f;

    // exact per-corner-predicated body (boundary samples)
    auto checked = [&](float sfv) {
        const float x = fmaf(sfv, dxs, bx);
        const float y = fmaf(sfv, dys, by);
        const float z = fmaf(sfv, dzs, bz);
        const float fx = floorf(x), fy = floorf(y), fz = floorf(z);
        const int ix = (int)fx, iy = (int)fy, iz = (int)fz;
        const float wx = x - fx, wy = y - fy, wz = z - fz;
        const bool x0 = (unsigned)ix       < 256u;
        const bool x1 = (unsigned)(ix + 1) < 256u;
        const bool y0 = (unsigned)iy       < 256u;
        const bool y1 = (unsigned)(iy + 1) < 256u;
        const bool z0 = (unsigned)iz       < 256u;
        const bool z1 = (unsigned)(iz + 1) < 256u;
        const int bx0 = ix << 16, bx1 = (ix + 1) << 16;
        const int by0 = iy << 8,  by1 = (iy + 1) << 8;
        const float c000 = (x0 && y0 && z0) ? vol[bx0 + by0 + iz]     : 0.0f;
        const float c001 = (x0 && y0 && z1) ? vol[bx0 + by0 + iz + 1] : 0.0f;
        const float c010 = (x0 && y1 && z0) ? vol[bx0 + by1 + iz]     : 0.0f;
        const float c011 = (x0 && y1 && z1) ? vol[bx0 + by1 + iz + 1] : 0.0f;
        const float c100 = (x1 && y0 && z0) ? vol[bx1 + by0 + iz]     : 0.0f;
        const float c101 = (x1 && y0 && z1) ? vol[bx1 + by0 + iz + 1] : 0.0f;
        const float c110 = (x1 && y1 && z0) ? vol[bx1 + by1 + iz]     : 0.0f;
        const float c111 = (x1 && y1 && z1) ? vol[bx1 + by1 + iz + 1] : 0.0f;
        const float c00 = fmaf(wz, c001 - c000, c000);
        const float c01 = fmaf(wz, c011 - c010, c010);
        const float c10 = fmaf(wz, c101 - c100, c100);
        const float c11 = fmaf(wz, c111 - c110, c110);
        const float c0  = fmaf(wy, c01 - c00, c00);
        const float c1  = fmaf(wy, c11 - c10, c10);
        acc += fmaf(wx, c1 - c0, c0);
    };

    // checked prologue (entry boundary)
    for (; s < sA_end; s += KPH, sf += (float)KPH) checked(sf);

    // fast interior loop: no bounds checks, flat fp32 index, saddr loads
    #pragma unroll 4
    for (; s <= sB_end; s += KPH, sf += (float)KPH) {
        const float x = fmaf(sf, dxs, bx);
        const float y = fmaf(sf, dys, by);
        const float z = fmaf(sf, dzs, bz);
        const float fx = floorf(x), fy = floorf(y), fz = floorf(z);
        const float wx = x - fx, wy = y - fy, wz = z - fz;
        // exact in fp32: max value 254*65536+254*256+254 < 2^24
        const unsigned idx = (unsigned)(int)fmaf(fx, 65536.0f, fmaf(fy, 256.0f, fz));
        const float* pb = vol + idx;
        const float c000 = pb[0];         const float c001 = pb[1];
        const float c010 = pb[256];       const float c011 = pb[257];
        const float c100 = pb[65536];     const float c101 = pb[65537];
        const float c110 = pb[65536+256]; const float c111 = pb[65536+257];
        const float c00 = fmaf(wz, c001 - c000, c000);
        const float c01 = fmaf(wz, c011 - c010, c010);
        const float c10 = fmaf(wz, c101 - c100, c100);
        const float c11 = fmaf(wz, c111 - c110, c110);
        const float c0  = fmaf(wy, c01 - c00, c00);
        const float c1  = fmaf(wy, c11 - c10, c10);
        acc += fmaf(wx, c1 - c0, c0);
    }

    // checked epilogue (exit boundary)
    for (; s <= s_hi; s += KPH, sf += (float)KPH) checked(sf);

    // reduce the 8 phases of this pixel (contiguous lanes)
    acc += __shfl_down(acc, 4, KPH);
    acc += __shfl_down(acc, 2, KPH);
    acc += __shfl_down(acc, 1, KPH);

    if (phase == 0) {
        const float step = sqrtf(rx*rx + ry*ry + rz*rz) * invN1;
        out[p] = acc * step;
    }
}

extern "C" void kernel_launch(void* const* d_in, const int* in_sizes, int n_in,
                              void* d_out, int out_size, void* d_ws, size_t ws_size,
                              hipStream_t stream) {
    const float* vol  = (const float*)d_in[0];
    const float* kinv = (const float*)d_in[1];
    const float* rt   = (const float*)d_in[2];
    const float* sdd  = (const float*)d_in[3];
    const float* aff  = (const float*)d_in[4];
    const int*   nsp  = (const int*)d_in[5];
    float* out = (float*)d_out;

    dim3 block(256);
    dim3 grid(NBLK);   // 1250 blocks * 32 pixels/block = 40000 pixels
    drr_kernel<<<grid, block, 0, stream>>>(vol, kinv, rt, sdd, aff, nsp, out);
}

// Round 3
// 113.636 us; speedup vs baseline: 1.0004x; 1.0004x over previous
//
#include <hip/hip_runtime.h>

#define IMG_H 200
#define IMG_W 200
#define VOLD  256          // volume is 256^3, strides: x<<16, y<<8, z
#define KPH   8            // threads (phases) per pixel
#define PPB   (256 / KPH)  // 32 pixels per 256-thread block
#define NPIX  (IMG_H * IMG_W)
#define NBLK  (NPIX / PPB) // 1250 (exact)
#define NXCD  8

__global__ __launch_bounds__(256) void drr_kernel(
    const float* __restrict__ vol,
    const float* __restrict__ kinv,   // [3][3]
    const float* __restrict__ rt,     // [4][4]
    const float* __restrict__ sddp,   // [1]
    const float* __restrict__ aff,    // [4][4]
    const int*   __restrict__ nsp,    // [1]
    float*       __restrict__ out)    // [H*W]
{
    // bijective XCD-chunked swizzle (m204): contiguous detector rows per XCD
    int b = blockIdx.x;
    {
        const int q = NBLK / NXCD;          // 156
        const int r = NBLK % NXCD;          // 2
        const int xcd = b % NXCD;
        const int idx = b / NXCD;
        b = (xcd < r) ? xcd * (q + 1) + idx
                      : r * (q + 1) + (xcd - r) * q + idx;
    }

    const int p     = b * PPB + ((int)threadIdx.x >> 3);  // pixel index
    const int phase = (int)threadIdx.x & (KPH - 1);
    if (p >= NPIX) return;

    const int   N     = nsp[0];
    const float sdd   = sddp[0];
    const float invN1 = 1.0f / (float)(N - 1);

    const float u = (float)(p % IMG_W);
    const float v = (float)(p / IMG_W);

    // tgt_cam = K^-1 * (u,v,1) * sdd
    const float tcx = (kinv[0]*u + kinv[1]*v + kinv[2]) * sdd;
    const float tcy = (kinv[3]*u + kinv[4]*v + kinv[5]) * sdd;
    const float tcz = (kinv[6]*u + kinv[7]*v + kinv[8]) * sdd;

    // ray = R * tgt_cam ; src = t
    const float rx = rt[0]*tcx + rt[1]*tcy + rt[2]*tcz;
    const float ry = rt[4]*tcx + rt[5]*tcy + rt[6]*tcz;
    const float rz = rt[8]*tcx + rt[9]*tcy + rt[10]*tcz;
    const float sx = rt[3], sy = rt[7], sz = rt[11];

    // voxel-space: vox(t) = base + t * dir
    const float bx = aff[0]*sx + aff[1]*sy + aff[2]*sz  + aff[3];
    const float by = aff[4]*sx + aff[5]*sy + aff[6]*sz  + aff[7];
    const float bz = aff[8]*sx + aff[9]*sy + aff[10]*sz + aff[11];
    const float dx = aff[0]*rx + aff[1]*ry + aff[2]*rz;
    const float dy = aff[4]*rx + aff[5]*ry + aff[6]*rz;
    const float dz = aff[8]*rx + aff[9]*ry + aff[10]*rz;

    // per-SAMPLE steps (coords computed as fmaf(sf, d*s, b*) with integer sf)
    const float dxs = dx * invN1, dys = dy * invN1, dzs = dz * invN1;

    // ---- two clip windows from one rcp per axis:
    //  outer (-1, 256): sample may be nonzero
    //  inner (0.01, 254.95): ALL 8 corners provably in-bounds -> fast path
    float t0 = 0.0f, t1 = 1.0f;
    float u0 = 0.0f, u1 = 1.0f;
    {
        const float bs[3] = {bx, by, bz};
        const float ds[3] = {dx, dy, dz};
        #pragma unroll
        for (int d = 0; d < 3; ++d) {
            const float bq = bs[d];
            const float dd = ds[d];
            if (fabsf(dd) > 1e-20f) {
                const float rdd = __frcp_rn(dd);
                const float ta = (-1.0f   - bq) * rdd;
                const float tb = (256.0f  - bq) * rdd;
                t0 = fmaxf(t0, fminf(ta, tb));
                t1 = fminf(t1, fmaxf(ta, tb));
                const float ua = (0.01f   - bq) * rdd;
                const float ub = (254.95f - bq) * rdd;
                u0 = fmaxf(u0, fminf(ua, ub));
                u1 = fminf(u1, fmaxf(ua, ub));
            } else {
                if (bq <= -1.0f  || bq >= 256.0f)   { t0 = 1.0f; t1 = -1.0f; }
                if (bq <= 0.01f  || bq >= 254.95f)  { u0 = 1.0f; u1 = -1.0f; }
            }
        }
    }
    int s_lo = 0, s_hi = -1;
    if (t0 <= t1) {
        s_lo = max((int)floorf(t0 * (float)(N - 1)) - 1, 0);
        s_hi = min((int)ceilf (t1 * (float)(N - 1)) + 1, N - 1);
    }
    int s_in, s_out;
    if (u0 <= u1) {
        s_in  = (int)ceilf (u0 * (float)(N - 1)) + 1;   // conservative shrink
        s_out = (int)floorf(u1 * (float)(N - 1)) - 1;
    } else {
        s_in = s_hi + 1; s_out = s_lo - 1;              // no fast region
    }
    const int sA_end = min(s_in,  s_hi + 1);  // checked prologue: s <  sA_end
    const int sB_end = min(s_out, s_hi);      // fast interior:    s <= sB_end
                                              // checked epilogue: s <= s_hi

    int   s   = s_lo + phase;
    float sf  = (float)s;
    float acc = 0.0f;

    // exact per-corner-predicated body (boundary samples)
    auto checked = [&](float sfv) {
        const float x = fmaf(sfv, dxs, bx);
        const float y = fmaf(sfv, dys, by);
        const float z = fmaf(sfv, dzs, bz);
        const float fx = floorf(x), fy = floorf(y), fz = floorf(z);
        const int ix = (int)fx, iy = (int)fy, iz = (int)fz;
        const float wx = x - fx, wy = y - fy, wz = z - fz;
        const bool x0 = (unsigned)ix       < 256u;
        const bool x1 = (unsigned)(ix + 1) < 256u;
        const bool y0 = (unsigned)iy       < 256u;
        const bool y1 = (unsigned)(iy + 1) < 256u;
        const bool z0 = (unsigned)iz       < 256u;
        const bool z1 = (unsigned)(iz + 1) < 256u;
        const int bx0 = ix << 16, bx1 = (ix + 1) << 16;
        const int by0 = iy << 8,  by1 = (iy + 1) << 8;
        const float c000 = (x0 && y0 && z0) ? vol[bx0 + by0 + iz]     : 0.0f;
        const float c001 = (x0 && y0 && z1) ? vol[bx0 + by0 + iz + 1] : 0.0f;
        const float c010 = (x0 && y1 && z0) ? vol[bx0 + by1 + iz]     : 0.0f;
        const float c011 = (x0 && y1 && z1) ? vol[bx0 + by1 + iz + 1] : 0.0f;
        const float c100 = (x1 && y0 && z0) ? vol[bx1 + by0 + iz]     : 0.0f;
        const float c101 = (x1 && y0 && z1) ? vol[bx1 + by0 + iz + 1] : 0.0f;
        const float c110 = (x1 && y1 && z0) ? vol[bx1 + by1 + iz]     : 0.0f;
        const float c111 = (x1 && y1 && z1) ? vol[bx1 + by1 + iz + 1] : 0.0f;
        const float c00 = fmaf(wz, c001 - c000, c000);
        const float c01 = fmaf(wz, c011 - c010, c010);
        const float c10 = fmaf(wz, c101 - c100, c100);
        const float c11 = fmaf(wz, c111 - c110, c110);
        const float c0  = fmaf(wy, c01 - c00, c00);
        const float c1  = fmaf(wy, c11 - c10, c10);
        acc += fmaf(wx, c1 - c0, c0);
    };

    // checked prologue (entry boundary)
    for (; s < sA_end; s += KPH, sf += (float)KPH) checked(sf);

    // ---- fast interior, 2 samples per iteration, ALL loads issued before
    // either trilerp (explicit MLP: 16 loads in flight; unroll 2 -> 32).
    #pragma unroll 2
    for (; s + KPH <= sB_end; s += 2 * KPH, sf += (float)(2 * KPH)) {
        const float sg = sf + (float)KPH;
        const float xA = fmaf(sf, dxs, bx), yA = fmaf(sf, dys, by), zA = fmaf(sf, dzs, bz);
        const float xB = fmaf(sg, dxs, bx), yB = fmaf(sg, dys, by), zB = fmaf(sg, dzs, bz);
        const float fxA = floorf(xA), fyA = floorf(yA), fzA = floorf(zA);
        const float fxB = floorf(xB), fyB = floorf(yB), fzB = floorf(zB);
        const float wxA = xA - fxA, wyA = yA - fyA, wzA = zA - fzA;
        const float wxB = xB - fxB, wyB = yB - fyB, wzB = zB - fzB;
        // exact in fp32: max index 254*65536+254*256+254 < 2^24
        const float* pA = vol + (unsigned)(int)fmaf(fxA, 65536.0f, fmaf(fyA, 256.0f, fzA));
        const float* pB = vol + (unsigned)(int)fmaf(fxB, 65536.0f, fmaf(fyB, 256.0f, fzB));

        const float a000 = pA[0];         const float a001 = pA[1];
        const float a010 = pA[256];       const float a011 = pA[257];
        const float a100 = pA[65536];     const float a101 = pA[65537];
        const float a110 = pA[65536+256]; const float a111 = pA[65536+257];
        const float b000 = pB[0];         const float b001 = pB[1];
        const float b010 = pB[256];       const float b011 = pB[257];
        const float b100 = pB[65536];     const float b101 = pB[65537];
        const float b110 = pB[65536+256]; const float b111 = pB[65536+257];

        const float a00 = fmaf(wzA, a001 - a000, a000);
        const float a01 = fmaf(wzA, a011 - a010, a010);
        const float a10 = fmaf(wzA, a101 - a100, a100);
        const float a11 = fmaf(wzA, a111 - a110, a110);
        const float a0  = fmaf(wyA, a01 - a00, a00);
        const float a1  = fmaf(wyA, a11 - a10, a10);
        acc += fmaf(wxA, a1 - a0, a0);

        const float b00 = fmaf(wzB, b001 - b000, b000);
        const float b01 = fmaf(wzB, b011 - b010, b010);
        const float b10 = fmaf(wzB, b101 - b100, b100);
        const float b11 = fmaf(wzB, b111 - b110, b110);
        const float b0  = fmaf(wyB, b01 - b00, b00);
        const float b1  = fmaf(wyB, b11 - b10, b10);
        acc += fmaf(wxB, b1 - b0, b0);
    }

    // leftover single fast sample
    for (; s <= sB_end; s += KPH, sf += (float)KPH) {
        const float x = fmaf(sf, dxs, bx);
        const float y = fmaf(sf, dys, by);
        const float z = fmaf(sf, dzs, bz);
        const float fx = floorf(x), fy = floorf(y), fz = floorf(z);
        const float wx = x - fx, wy = y - fy, wz = z - fz;
        const float* pb = vol + (unsigned)(int)fmaf(fx, 65536.0f, fmaf(fy, 256.0f, fz));
        const float c000 = pb[0];         const float c001 = pb[1];
        const float c010 = pb[256];       const float c011 = pb[257];
        const float c100 = pb[65536];     const float c101 = pb[65537];
        const float c110 = pb[65536+256]; const float c111 = pb[65536+257];
        const float c00 = fmaf(wz, c001 - c000, c000);
        const float c01 = fmaf(wz, c011 - c010, c010);
        const float c10 = fmaf(wz, c101 - c100, c100);
        const float c11 = fmaf(wz, c111 - c110, c110);
        const float c0  = fmaf(wy, c01 - c00, c00);
        const float c1  = fmaf(wy, c11 - c10, c10);
        acc += fmaf(wx, c1 - c0, c0);
    }

    // checked epilogue (exit boundary)
    for (; s <= s_hi; s += KPH, sf += (float)KPH) checked(sf);

    // reduce the 8 phases of this pixel (contiguous lanes)
    acc += __shfl_down(acc, 4, KPH);
    acc += __shfl_down(acc, 2, KPH);
    acc += __shfl_down(acc, 1, KPH);

    if (phase == 0) {
        const float step = sqrtf(rx*rx + ry*ry + rz*rz) * invN1;
        out[p] = acc * step;
    }
}

extern "C" void kernel_launch(void* const* d_in, const int* in_sizes, int n_in,
                              void* d_out, int out_size, void* d_ws, size_t ws_size,
                              hipStream_t stream) {
    const float* vol  = (const float*)d_in[0];
    const float* kinv = (const float*)d_in[1];
    const float* rt   = (const float*)d_in[2];
    const float* sdd  = (const float*)d_in[3];
    const float* aff  = (const float*)d_in[4];
    const int*   nsp  = (const int*)d_in[5];
    float* out = (float*)d_out;

    dim3 block(256);
    dim3 grid(NBLK);   // 1250 blocks * 32 pixels/block = 40000 pixels
    drr_kernel<<<grid, block, 0, stream>>>(vol, kinv, rt, sdd, aff, nsp, out);
}